// Round 1
// baseline (3299.743 us; speedup 1.0000x reference)
//
#include <hip/hip_runtime.h>
#include <hip/hip_bf16.h>

// Problem constants (from reference): N=50000, E=800000, D=128, H=256, A=16
#define N_NODES 50000
#define N_EDGES 800000
#define DIM_D   128
#define DIM_H   256
#define DIM_A   16

typedef unsigned short u16;
typedef __attribute__((ext_vector_type(4))) float f4;
typedef __attribute__((ext_vector_type(8))) short s8;

__device__ __forceinline__ u16 f2bf(float f) {
    union { float f; unsigned u; } v; v.f = f;
    unsigned r = v.u + 0x7FFFu + ((v.u >> 16) & 1u);   // RNE
    return (u16)(r >> 16);
}
__device__ __forceinline__ float bf2f(u16 s) {
    union { unsigned u; float f; } v; v.u = ((unsigned)s) << 16; return v.f;
}
__device__ __forceinline__ s8 zero_s8() {
    s8 v;
#pragma unroll
    for (int i = 0; i < 8; i++) v[i] = 0;
    return v;
}

// ---------------- degree / norm ----------------
__global__ __launch_bounds__(256) void k_deg_init(float* deg) {
    int i = blockIdx.x * 256 + threadIdx.x;
    if (i < N_NODES) deg[i] = 1.0f;            // self-loop
}
__global__ __launch_bounds__(256) void k_deg_count(const int* __restrict__ coli, float* deg) {
    int e = blockIdx.x * 256 + threadIdx.x;
    if (e < N_EDGES) atomicAdd(&deg[coli[e]], 1.0f);
}
__global__ __launch_bounds__(256) void k_dinv(float* deg) {
    int i = blockIdx.x * 256 + threadIdx.x;
    if (i < N_NODES) deg[i] = rsqrtf(deg[i]);  // in-place -> dinv
}

// ---------------- weight transpose+cast: W[K][Nn] fp32 -> Wt[Nn][K] bf16 ----------------
__global__ __launch_bounds__(256) void k_twt(const float* __restrict__ W, u16* __restrict__ Wt,
                                             int K, int Nn) {
    int idx = blockIdx.x * 256 + threadIdx.x;
    if (idx >= K * Nn) return;
    int k = idx / Nn, n = idx - k * Nn;
    Wt[n * K + k] = f2bf(W[idx]);
}

// ---------------- self-loop init: z[n] = X[n] * dinv[n]^2 ----------------
template <bool SRC_BF16>
__global__ __launch_bounds__(256) void k_selfinit(const void* __restrict__ X,
                                                  const float* __restrict__ dinv,
                                                  float* __restrict__ z) {
    int gid = blockIdx.x * 256 + threadIdx.x;
    if (gid >= N_NODES * 32) return;
    int n = gid >> 5, c4 = (gid & 31) * 4;
    float di = dinv[n];
    float s = di * di;
    float4 v;
    if (SRC_BF16) {
        const u16* xp = (const u16*)X;
        ushort4 u = *(const ushort4*)&xp[(size_t)n * DIM_D + c4];
        v = make_float4(bf2f(u.x), bf2f(u.y), bf2f(u.z), bf2f(u.w));
    } else {
        v = *(const float4*)&((const float*)X)[(size_t)n * DIM_D + c4];
    }
    *(float4*)&z[(size_t)n * DIM_D + c4] = make_float4(v.x * s, v.y * s, v.z * s, v.w * s);
}

// ---------------- scatter: z[col] += X[row] * dinv[row]*dinv[col] ----------------
template <bool SRC_BF16>
__global__ __launch_bounds__(256) void k_scatter(const void* __restrict__ X,
                                                 const int* __restrict__ rowi,
                                                 const int* __restrict__ coli,
                                                 const float* __restrict__ dinv,
                                                 float* __restrict__ z) {
    int gid = blockIdx.x * 256 + threadIdx.x;   // E*32 threads, 32 per edge (4 cols each)
    int e = gid >> 5, c4 = (gid & 31) * 4;
    if (e >= N_EDGES) return;
    int r = rowi[e], c = coli[e];
    float nrm = dinv[r] * dinv[c];
    float4 v;
    if (SRC_BF16) {
        const u16* xp = (const u16*)X;
        ushort4 u = *(const ushort4*)&xp[(size_t)r * DIM_D + c4];
        v = make_float4(bf2f(u.x), bf2f(u.y), bf2f(u.z), bf2f(u.w));
    } else {
        v = *(const float4*)&((const float*)X)[(size_t)r * DIM_D + c4];
    }
    float* zp = &z[(size_t)c * DIM_D + c4];
    atomicAdd(zp + 0, v.x * nrm);
    atomicAdd(zp + 1, v.y * nrm);
    atomicAdd(zp + 2, v.z * nrm);
    atomicAdd(zp + 3, v.w * nrm);
}

// ---------------- MFMA GEMM: C[M][Nn] = post(A[M][K] @ W + postB), W given as Wt[Nn][K] bf16 ----
// A_BF16: A is bf16[M][K] else fp32. PRE_BR: A' = relu(A + preB[k]) before cast.
#define BM 128
#define BN 64
#define BK 32
#define BKP 56   // padded K stride in LDS (bf16 elems); 112B rows -> ~2-way banks, 16B aligned

template <bool A_BF16, bool PRE_BR, bool POST_RELU, bool OUT_BF16>
__global__ __launch_bounds__(256) void k_gemm(const void* __restrict__ Ap,
                                              const u16* __restrict__ Wt,
                                              const float* __restrict__ preB,
                                              const float* __restrict__ postB,
                                              void* __restrict__ Cp,
                                              int M, int K, int Nn) {
    __shared__ __align__(16) u16 As[BM * BKP];
    __shared__ __align__(16) u16 Bs[BN * BKP];
    const int tid = threadIdx.x;
    const int wid = tid >> 6, lane = tid & 63;
    const int q = lane >> 4, l = lane & 15;
    const int bm = blockIdx.x * BM, bn = blockIdx.y * BN;

    f4 acc[8];
#pragma unroll
    for (int i = 0; i < 8; i++) { f4 zz = {0.f, 0.f, 0.f, 0.f}; acc[i] = zz; }

    for (int k0 = 0; k0 < K; k0 += BK) {
        __syncthreads();
        // stage W tile: Bs[n][k], n in [bn,bn+64), k in [k0,k0+32)
        {
            int n = tid >> 2, kc = (tid & 3) * 8;
            *(int4*)&Bs[n * BKP + kc] = *(const int4*)&Wt[(size_t)(bn + n) * K + k0 + kc];
        }
        // stage A tile: As[m][k]
        if (A_BF16) {
            const u16* A = (const u16*)Ap;
#pragma unroll
            for (int p = 0; p < 2; p++) {
                int m = (tid >> 2) + p * 64, kc = (tid & 3) * 8;
                int gm = bm + m; if (gm >= M) gm = M - 1;
                *(int4*)&As[m * BKP + kc] = *(const int4*)&A[(size_t)gm * K + k0 + kc];
            }
        } else {
            const float* A = (const float*)Ap;
#pragma unroll
            for (int p = 0; p < 4; p++) {
                int m = (tid >> 3) + p * 32, k4 = (tid & 7) * 4;
                int gm = bm + m; if (gm >= M) gm = M - 1;
                float4 v = *(const float4*)&A[(size_t)gm * K + k0 + k4];
                if (PRE_BR) {
                    const float4 pb = *(const float4*)&preB[k0 + k4];
                    v.x = fmaxf(v.x + pb.x, 0.f);
                    v.y = fmaxf(v.y + pb.y, 0.f);
                    v.z = fmaxf(v.z + pb.z, 0.f);
                    v.w = fmaxf(v.w + pb.w, 0.f);
                }
                ushort4 o;
                o.x = f2bf(v.x); o.y = f2bf(v.y); o.z = f2bf(v.z); o.w = f2bf(v.w);
                *(ushort4*)&As[m * BKP + k4] = o;
            }
        }
        __syncthreads();

        s8 af[2], bf[4];
#pragma unroll
        for (int mt = 0; mt < 2; mt++)
            af[mt] = *(const s8*)&As[(wid * 32 + mt * 16 + l) * BKP + q * 8];
#pragma unroll
        for (int nt = 0; nt < 4; nt++)
            bf[nt] = *(const s8*)&Bs[(nt * 16 + l) * BKP + q * 8];
#pragma unroll
        for (int mt = 0; mt < 2; mt++)
#pragma unroll
            for (int nt = 0; nt < 4; nt++)
                acc[mt * 4 + nt] = __builtin_amdgcn_mfma_f32_16x16x32_bf16(
                    af[mt], bf[nt], acc[mt * 4 + nt], 0, 0, 0);
    }

    // epilogue: C row = q*4+r, col = l (per 16x16 tile)
#pragma unroll
    for (int mt = 0; mt < 2; mt++) {
#pragma unroll
        for (int nt = 0; nt < 4; nt++) {
            int colg = bn + nt * 16 + l;
            float pb = postB ? postB[colg] : 0.0f;
#pragma unroll
            for (int r = 0; r < 4; r++) {
                int rowg = bm + wid * 32 + mt * 16 + q * 4 + r;
                if (rowg < M) {
                    float v = acc[mt * 4 + nt][r] + pb;
                    if (POST_RELU) v = fmaxf(v, 0.f);
                    if (OUT_BF16)
                        ((u16*)Cp)[(size_t)rowg * Nn + colg] = f2bf(v);
                    else
                        ((float*)Cp)[(size_t)rowg * Nn + colg] = v;
                }
            }
        }
    }
}

// ---------------- edge predictor: 16 edges per wave, MFMA for attr@Wc and u@We2 --------------
// t[16][256] = P[row] + Q[col] + attr@Wc ; u = relu(t) ; out[16][16] = u@We2 + be2
__global__ __launch_bounds__(256) void k_edge(const u16* __restrict__ P, const u16* __restrict__ Q,
                                              const float* __restrict__ attr,
                                              const int* __restrict__ rowi,
                                              const int* __restrict__ coli,
                                              const u16* __restrict__ Wct,   // [256][16] bf16
                                              const u16* __restrict__ We2t,  // [16][256] bf16
                                              const float* __restrict__ be2,
                                              float* __restrict__ outp) {
    __shared__ __align__(16) u16 ub[4][16][272];   // per-wave u tile, padded rows
    const int tid = threadIdx.x, wid = tid >> 6, lane = tid & 63;
    const int q = lane >> 4, l = lane & 15;
    const float be2v = be2[l];
    u16(*u)[272] = ub[wid];

    for (int tile = blockIdx.x * 4 + wid; tile < N_EDGES / 16; tile += gridDim.x * 4) {
        const int e0 = tile * 16;
        // 1: pq[e][c] = P[row[e]][c] + Q[col[e]][c]  (c = lane*4 .. +3, coalesced 512B rows)
#pragma unroll 4
        for (int ee = 0; ee < 16; ee++) {
            int e = e0 + ee;
            int r = rowi[e], c = coli[e];
            ushort4 pu = *(const ushort4*)&P[(size_t)r * DIM_H + lane * 4];
            ushort4 qu = *(const ushort4*)&Q[(size_t)c * DIM_H + lane * 4];
            ushort4 s;
            s.x = f2bf(bf2f(pu.x) + bf2f(qu.x));
            s.y = f2bf(bf2f(pu.y) + bf2f(qu.y));
            s.z = f2bf(bf2f(pu.z) + bf2f(qu.z));
            s.w = f2bf(bf2f(pu.w) + bf2f(qu.w));
            *(ushort4*)&u[ee][lane * 4] = s;
        }
        // 2: attr A-frag (M=16 edges, K=16 padded to 32 with zeros)
        s8 af = zero_s8();
        if (q < 2) {
            const float* ap = &attr[(size_t)(e0 + l) * DIM_A + q * 8];
            float4 a0 = *(const float4*)ap;
            float4 a1 = *(const float4*)(ap + 4);
            af[0] = (short)f2bf(a0.x); af[1] = (short)f2bf(a0.y);
            af[2] = (short)f2bf(a0.z); af[3] = (short)f2bf(a0.w);
            af[4] = (short)f2bf(a1.x); af[5] = (short)f2bf(a1.y);
            af[6] = (short)f2bf(a1.z); af[7] = (short)f2bf(a1.w);
        }
        // 3: attr @ Wc -> acc[nt] over 256 hidden cols
        f4 acc[16];
#pragma unroll
        for (int nt = 0; nt < 16; nt++) {
            s8 bf = zero_s8();
            if (q < 2) bf = *(const s8*)&Wct[(nt * 16 + l) * 16 + q * 8];
            f4 cz = {0.f, 0.f, 0.f, 0.f};
            acc[nt] = __builtin_amdgcn_mfma_f32_16x16x32_bf16(af, bf, cz, 0, 0, 0);
        }
        // 4: t = acc + pq ; relu ; write u back (bf16) in place
#pragma unroll
        for (int nt = 0; nt < 16; nt++) {
#pragma unroll
            for (int r = 0; r < 4; r++) {
                int er = q * 4 + r, col = nt * 16 + l;
                float t = acc[nt][r] + bf2f(u[er][col]);
                u[er][col] = f2bf(fmaxf(t, 0.f));
            }
        }
        // 5: out = u @ We2 (M=16 edges, N=16, K=256)
        f4 acc2 = {0.f, 0.f, 0.f, 0.f};
#pragma unroll
        for (int ks = 0; ks < 8; ks++) {
            s8 uf = *(const s8*)&u[l][ks * 32 + q * 8];
            s8 wf = *(const s8*)&We2t[(size_t)l * DIM_H + ks * 32 + q * 8];
            acc2 = __builtin_amdgcn_mfma_f32_16x16x32_bf16(uf, wf, acc2, 0, 0, 0);
        }
        // 6: store (row=edge q*4+r, col=l)
#pragma unroll
        for (int r = 0; r < 4; r++) {
            int e = e0 + q * 4 + r;
            outp[(size_t)e * DIM_A + l] = acc2[r] + be2v;
        }
    }
}

extern "C" void kernel_launch(void* const* d_in, const int* in_sizes, int n_in,
                              void* d_out, int out_size, void* d_ws, size_t ws_size,
                              hipStream_t stream) {
    (void)in_sizes; (void)n_in; (void)out_size; (void)ws_size;
    const float* x    = (const float*)d_in[0];
    const int*   ei   = (const int*)d_in[1];
    const float* attr = (const float*)d_in[2];
    const float* W1   = (const float*)d_in[3];
    const float* b1   = (const float*)d_in[4];
    const float* W2   = (const float*)d_in[5];
    const float* b2   = (const float*)d_in[6];
    const float* Wo1  = (const float*)d_in[7];
    const float* bo1  = (const float*)d_in[8];
    const float* Wo2  = (const float*)d_in[9];
    const float* bo2  = (const float*)d_in[10];
    const float* We1  = (const float*)d_in[11];
    const float* be1  = (const float*)d_in[12];
    const float* We2  = (const float*)d_in[13];
    const float* be2  = (const float*)d_in[14];
    const int* rowi = ei;
    const int* coli = ei + N_EDGES;

    float* hout = (float*)d_out;                       // [N][128]
    float* eout = hout + (size_t)N_NODES * DIM_D;      // [E][16]

    char* ws = (char*)d_ws;
    size_t off = 0;
    auto nxt = [&](size_t b) -> void* {
        void* p = ws + off; off = (off + b + 255) & ~(size_t)255; return p;
    };
    float* dinv = (float*)nxt((size_t)N_NODES * 4);
    u16* W1t  = (u16*)nxt(128 * 256 * 2);
    u16* W2t  = (u16*)nxt(128 * 256 * 2);
    u16* Wo1t = (u16*)nxt(128 * 256 * 2);
    u16* Wo2t = (u16*)nxt(128 * 256 * 2);
    u16* Wat  = (u16*)nxt(128 * 256 * 2);
    u16* Wbt  = (u16*)nxt(128 * 256 * 2);
    u16* Wct  = (u16*)nxt(256 * 16 * 2);
    u16* We2t = (u16*)nxt(16 * 256 * 2);
    float* z  = (float*)nxt((size_t)N_NODES * DIM_D * 4);   // Âx / Ây accumulator (fp32)
    u16* h1   = (u16*)nxt((size_t)N_NODES * DIM_H * 2);     // reused: h1 -> h3 -> P
    u16* yb   = (u16*)nxt((size_t)N_NODES * DIM_D * 2);
    u16* Qb   = (u16*)nxt((size_t)N_NODES * DIM_H * 2);
    // total ws use: ~91 MB

    // weight transposes (bf16)
    k_twt<<<(128 * 256 + 255) / 256, 256, 0, stream>>>(W1, W1t, 128, 256);
    k_twt<<<(128 * 256 + 255) / 256, 256, 0, stream>>>(W2, W2t, 256, 128);
    k_twt<<<(128 * 256 + 255) / 256, 256, 0, stream>>>(Wo1, Wo1t, 128, 256);
    k_twt<<<(128 * 256 + 255) / 256, 256, 0, stream>>>(Wo2, Wo2t, 256, 128);
    k_twt<<<(128 * 256 + 255) / 256, 256, 0, stream>>>(We1, Wat, 128, 256);
    k_twt<<<(128 * 256 + 255) / 256, 256, 0, stream>>>(We1 + 128 * 256, Wbt, 128, 256);
    k_twt<<<(16 * 256 + 255) / 256, 256, 0, stream>>>(We1 + 256 * 256, Wct, 16, 256);
    k_twt<<<(16 * 256 + 255) / 256, 256, 0, stream>>>(We2, We2t, 256, 16);

    // symmetric norm
    k_deg_init<<<(N_NODES + 255) / 256, 256, 0, stream>>>(dinv);
    k_deg_count<<<(N_EDGES + 255) / 256, 256, 0, stream>>>(coli, dinv);
    k_dinv<<<(N_NODES + 255) / 256, 256, 0, stream>>>(dinv);

    dim3 g4(391, 4), g2(391, 2);
    // layer 1: z = Âx ; h1 = relu(z@W1 + b1)
    k_selfinit<false><<<N_NODES * 32 / 256, 256, 0, stream>>>(x, dinv, z);
    k_scatter<false><<<N_EDGES * 32 / 256, 256, 0, stream>>>(x, rowi, coli, dinv, z);
    k_gemm<false, false, true, true><<<g4, 256, 0, stream>>>(z, W1t, nullptr, b1, h1, N_NODES, 128, 256);
    // layer 2: y = h1@W2 ; z = Ây ; h2 = relu(z + b2) fused into next GEMM's A-stage
    k_gemm<true, false, false, true><<<g2, 256, 0, stream>>>(h1, W2t, nullptr, nullptr, yb, N_NODES, 256, 128);
    k_selfinit<true><<<N_NODES * 32 / 256, 256, 0, stream>>>(yb, dinv, z);
    k_scatter<true><<<N_EDGES * 32 / 256, 256, 0, stream>>>(yb, rowi, coli, dinv, z);
    // output MLP: h3 = relu(relu(z+b2)@Wo1 + bo1) ; h = h3@Wo2 + bo2 -> d_out (fp32)
    k_gemm<false, true, true, true><<<g4, 256, 0, stream>>>(z, Wo1t, b2, bo1, h1, N_NODES, 128, 256);
    k_gemm<true, false, false, false><<<g2, 256, 0, stream>>>(h1, Wo2t, nullptr, bo2, hout, N_NODES, 256, 128);
    // edge predictor precompute: P = h@Wa + be1 ; Q = h@Wb (bf16)
    k_gemm<false, false, false, true><<<g4, 256, 0, stream>>>(hout, Wat, nullptr, be1, h1, N_NODES, 128, 256);
    k_gemm<false, false, false, true><<<g4, 256, 0, stream>>>(hout, Wbt, nullptr, nullptr, Qb, N_NODES, 128, 256);
    // per-edge: out = relu(P[r]+Q[c]+attr@Wc)@We2 + be2
    k_edge<<<1024, 256, 0, stream>>>(h1, Qb, attr, rowi, coli, Wct, We2t, be2, eout);
}

// Round 2
// 849.428 us; speedup vs baseline: 3.8847x; 3.8847x over previous
//
#include <hip/hip_runtime.h>
#include <hip/hip_bf16.h>

// Problem constants (from reference): N=50000, E=800000, D=128, H=256, A=16
#define N_NODES 50000
#define N_EDGES 800000
#define DIM_D   128
#define DIM_H   256
#define DIM_A   16

typedef unsigned short u16;
typedef __attribute__((ext_vector_type(4))) float f4;
typedef __attribute__((ext_vector_type(8))) short s8;

__device__ __forceinline__ u16 f2bf(float f) {
    union { float f; unsigned u; } v; v.f = f;
    unsigned r = v.u + 0x7FFFu + ((v.u >> 16) & 1u);   // RNE
    return (u16)(r >> 16);
}
__device__ __forceinline__ float bf2f(u16 s) {
    union { unsigned u; float f; } v; v.u = ((unsigned)s) << 16; return v.f;
}
__device__ __forceinline__ s8 zero_s8() {
    s8 v;
#pragma unroll
    for (int i = 0; i < 8; i++) v[i] = 0;
    return v;
}

// ---------------- CSR build ----------------
__global__ __launch_bounds__(256) void k_zero(int* __restrict__ cnt) {
    int i = blockIdx.x * 256 + threadIdx.x;
    if (i < N_NODES) cnt[i] = 0;
}
__global__ __launch_bounds__(256) void k_count(const int* __restrict__ coli, int* __restrict__ cnt) {
    int e = blockIdx.x * 256 + threadIdx.x;
    if (e < N_EDGES) atomicAdd(&cnt[coli[e]], 1);
}
__global__ __launch_bounds__(256) void k_dinv(const int* __restrict__ cnt, float* __restrict__ dinv) {
    int i = blockIdx.x * 256 + threadIdx.x;
    if (i < N_NODES) dinv[i] = rsqrtf((float)(cnt[i] + 1));   // +1 self-loop
}

#define SCAN_C 49   // 1024 * 49 = 50176 >= N_NODES
__global__ __launch_bounds__(1024) void k_scan(const int* __restrict__ cnt, int* __restrict__ start) {
    __shared__ int ps[1024];
    int t = threadIdx.x;
    int base = t * SCAN_C;
    int sum = 0;
    for (int i = 0; i < SCAN_C; i++) {
        int idx = base + i;
        sum += (idx < N_NODES) ? cnt[idx] : 0;
    }
    ps[t] = sum;
    __syncthreads();
    for (int ofs = 1; ofs < 1024; ofs <<= 1) {
        int v = (t >= ofs) ? ps[t - ofs] : 0;
        __syncthreads();
        ps[t] += v;
        __syncthreads();
    }
    int run = (t > 0) ? ps[t - 1] : 0;
    for (int i = 0; i < SCAN_C; i++) {
        int idx = base + i;
        if (idx < N_NODES) {
            start[idx] = run;
            run += cnt[idx];
        }
    }
    if (t == 1023) start[N_NODES] = ps[1023];
}
__global__ __launch_bounds__(256) void k_copy(const int* __restrict__ start, int* __restrict__ cursor) {
    int i = blockIdx.x * 256 + threadIdx.x;
    if (i < N_NODES) cursor[i] = start[i];
}
// pack[slot] = {src_node, dinv[src]*dinv[dst]} bucketed by destination
__global__ __launch_bounds__(256) void k_fill(const int* __restrict__ rowi, const int* __restrict__ coli,
                                              const float* __restrict__ dinv,
                                              int* __restrict__ cursor, int2* __restrict__ pack) {
    int e = blockIdx.x * 256 + threadIdx.x;
    if (e >= N_EDGES) return;
    int r = rowi[e], c = coli[e];
    int slot = atomicAdd(&cursor[c], 1);
    float w = dinv[r] * dinv[c];
    pack[slot] = make_int2(r, __float_as_int(w));
}

// ---------------- CSR gather: z[n] = X[n]*dinv[n]^2 + sum_{e->n} X[src]*w ----------------
// one wave per node; lane covers 2 of 128 cols
template <bool SRC_BF16>
__global__ __launch_bounds__(256) void k_gather(const void* __restrict__ X,
                                                const int2* __restrict__ pack,
                                                const int* __restrict__ start,
                                                const float* __restrict__ dinv,
                                                float* __restrict__ z) {
    int node = blockIdx.x * 4 + (threadIdx.x >> 6);
    if (node >= N_NODES) return;
    int lane = threadIdx.x & 63;
    int c2 = lane * 2;
    float di = dinv[node];
    float sl = di * di;
    float2 acc;
    if (SRC_BF16) {
        ushort2 u = *(const ushort2*)&((const u16*)X)[(size_t)node * DIM_D + c2];
        acc.x = bf2f(u.x) * sl; acc.y = bf2f(u.y) * sl;
    } else {
        float2 v = *(const float2*)&((const float*)X)[(size_t)node * DIM_D + c2];
        acc.x = v.x * sl; acc.y = v.y * sl;
    }
    int s = start[node], e = start[node + 1];
#pragma unroll 2
    for (int i = s; i < e; i++) {
        int2 p = pack[i];
        float w = __int_as_float(p.y);
        float2 v;
        if (SRC_BF16) {
            ushort2 u = *(const ushort2*)&((const u16*)X)[(size_t)p.x * DIM_D + c2];
            v.x = bf2f(u.x); v.y = bf2f(u.y);
        } else {
            v = *(const float2*)&((const float*)X)[(size_t)p.x * DIM_D + c2];
        }
        acc.x += v.x * w; acc.y += v.y * w;
    }
    *(float2*)&z[(size_t)node * DIM_D + c2] = acc;
}

// ---------------- weight transpose+cast: W[K][Nn] fp32 -> Wt[Nn][K] bf16 ----------------
__global__ __launch_bounds__(256) void k_twt(const float* __restrict__ W, u16* __restrict__ Wt,
                                             int K, int Nn) {
    int idx = blockIdx.x * 256 + threadIdx.x;
    if (idx >= K * Nn) return;
    int k = idx / Nn, n = idx - k * Nn;
    Wt[n * K + k] = f2bf(W[idx]);
}

// ---------------- MFMA GEMM: C[M][Nn] = post(A[M][K] @ W + postB), W given as Wt[Nn][K] bf16 ----
// A_BF16: A is bf16[M][K] else fp32. PRE_BR: A' = relu(A + preB[k]) before cast.
#define BM 128
#define BN 64
#define BK 32
#define BKP 56   // padded K stride in LDS (bf16 elems); 112B rows -> ~2-way banks, 16B aligned

template <bool A_BF16, bool PRE_BR, bool POST_RELU, bool OUT_BF16>
__global__ __launch_bounds__(256) void k_gemm(const void* __restrict__ Ap,
                                              const u16* __restrict__ Wt,
                                              const float* __restrict__ preB,
                                              const float* __restrict__ postB,
                                              void* __restrict__ Cp,
                                              int M, int K, int Nn) {
    __shared__ __align__(16) u16 As[BM * BKP];
    __shared__ __align__(16) u16 Bs[BN * BKP];
    const int tid = threadIdx.x;
    const int wid = tid >> 6, lane = tid & 63;
    const int q = lane >> 4, l = lane & 15;
    const int bm = blockIdx.x * BM, bn = blockIdx.y * BN;

    f4 acc[8];
#pragma unroll
    for (int i = 0; i < 8; i++) { f4 zz = {0.f, 0.f, 0.f, 0.f}; acc[i] = zz; }

    for (int k0 = 0; k0 < K; k0 += BK) {
        __syncthreads();
        // stage W tile: Bs[n][k], n in [bn,bn+64), k in [k0,k0+32)
        {
            int n = tid >> 2, kc = (tid & 3) * 8;
            *(int4*)&Bs[n * BKP + kc] = *(const int4*)&Wt[(size_t)(bn + n) * K + k0 + kc];
        }
        // stage A tile: As[m][k]
        if (A_BF16) {
            const u16* A = (const u16*)Ap;
#pragma unroll
            for (int p = 0; p < 2; p++) {
                int m = (tid >> 2) + p * 64, kc = (tid & 3) * 8;
                int gm = bm + m; if (gm >= M) gm = M - 1;
                *(int4*)&As[m * BKP + kc] = *(const int4*)&A[(size_t)gm * K + k0 + kc];
            }
        } else {
            const float* A = (const float*)Ap;
#pragma unroll
            for (int p = 0; p < 4; p++) {
                int m = (tid >> 3) + p * 32, k4 = (tid & 7) * 4;
                int gm = bm + m; if (gm >= M) gm = M - 1;
                float4 v = *(const float4*)&A[(size_t)gm * K + k0 + k4];
                if (PRE_BR) {
                    const float4 pb = *(const float4*)&preB[k0 + k4];
                    v.x = fmaxf(v.x + pb.x, 0.f);
                    v.y = fmaxf(v.y + pb.y, 0.f);
                    v.z = fmaxf(v.z + pb.z, 0.f);
                    v.w = fmaxf(v.w + pb.w, 0.f);
                }
                ushort4 o;
                o.x = f2bf(v.x); o.y = f2bf(v.y); o.z = f2bf(v.z); o.w = f2bf(v.w);
                *(ushort4*)&As[m * BKP + k4] = o;
            }
        }
        __syncthreads();

        s8 af[2], bf[4];
#pragma unroll
        for (int mt = 0; mt < 2; mt++)
            af[mt] = *(const s8*)&As[(wid * 32 + mt * 16 + l) * BKP + q * 8];
#pragma unroll
        for (int nt = 0; nt < 4; nt++)
            bf[nt] = *(const s8*)&Bs[(nt * 16 + l) * BKP + q * 8];
#pragma unroll
        for (int mt = 0; mt < 2; mt++)
#pragma unroll
            for (int nt = 0; nt < 4; nt++)
                acc[mt * 4 + nt] = __builtin_amdgcn_mfma_f32_16x16x32_bf16(
                    af[mt], bf[nt], acc[mt * 4 + nt], 0, 0, 0);
    }

    // epilogue: C row = q*4+r, col = l (per 16x16 tile)
#pragma unroll
    for (int mt = 0; mt < 2; mt++) {
#pragma unroll
        for (int nt = 0; nt < 4; nt++) {
            int colg = bn + nt * 16 + l;
            float pb = postB ? postB[colg] : 0.0f;
#pragma unroll
            for (int r = 0; r < 4; r++) {
                int rowg = bm + wid * 32 + mt * 16 + q * 4 + r;
                if (rowg < M) {
                    float v = acc[mt * 4 + nt][r] + pb;
                    if (POST_RELU) v = fmaxf(v, 0.f);
                    if (OUT_BF16)
                        ((u16*)Cp)[(size_t)rowg * Nn + colg] = f2bf(v);
                    else
                        ((float*)Cp)[(size_t)rowg * Nn + colg] = v;
                }
            }
        }
    }
}

// ---------------- edge predictor: 16 edges per wave, MFMA for attr@Wc and u@We2 --------------
// t[16][256] = P[row] + Q[col] + attr@Wc ; u = relu(t) ; out[16][16] = u@We2 + be2
__global__ __launch_bounds__(256) void k_edge(const u16* __restrict__ P, const u16* __restrict__ Q,
                                              const float* __restrict__ attr,
                                              const int* __restrict__ rowi,
                                              const int* __restrict__ coli,
                                              const u16* __restrict__ Wct,   // [256][16] bf16
                                              const u16* __restrict__ We2t,  // [16][256] bf16
                                              const float* __restrict__ be2,
                                              float* __restrict__ outp) {
    __shared__ __align__(16) u16 ub[4][16][272];   // per-wave u tile, padded rows
    const int tid = threadIdx.x, wid = tid >> 6, lane = tid & 63;
    const int q = lane >> 4, l = lane & 15;
    const float be2v = be2[l];
    u16(*u)[272] = ub[wid];

    for (int tile = blockIdx.x * 4 + wid; tile < N_EDGES / 16; tile += gridDim.x * 4) {
        const int e0 = tile * 16;
        // 1: pq[e][c] = P[row[e]][c] + Q[col[e]][c]  (c = lane*4 .. +3, coalesced 512B rows)
#pragma unroll 4
        for (int ee = 0; ee < 16; ee++) {
            int e = e0 + ee;
            int r = rowi[e], c = coli[e];
            ushort4 pu = *(const ushort4*)&P[(size_t)r * DIM_H + lane * 4];
            ushort4 qu = *(const ushort4*)&Q[(size_t)c * DIM_H + lane * 4];
            ushort4 s;
            s.x = f2bf(bf2f(pu.x) + bf2f(qu.x));
            s.y = f2bf(bf2f(pu.y) + bf2f(qu.y));
            s.z = f2bf(bf2f(pu.z) + bf2f(qu.z));
            s.w = f2bf(bf2f(pu.w) + bf2f(qu.w));
            *(ushort4*)&u[ee][lane * 4] = s;
        }
        // 2: attr A-frag (M=16 edges, K=16 padded to 32 with zeros)
        s8 af = zero_s8();
        if (q < 2) {
            const float* ap = &attr[(size_t)(e0 + l) * DIM_A + q * 8];
            float4 a0 = *(const float4*)ap;
            float4 a1 = *(const float4*)(ap + 4);
            af[0] = (short)f2bf(a0.x); af[1] = (short)f2bf(a0.y);
            af[2] = (short)f2bf(a0.z); af[3] = (short)f2bf(a0.w);
            af[4] = (short)f2bf(a1.x); af[5] = (short)f2bf(a1.y);
            af[6] = (short)f2bf(a1.z); af[7] = (short)f2bf(a1.w);
        }
        // 3: attr @ Wc -> acc[nt] over 256 hidden cols
        f4 acc[16];
#pragma unroll
        for (int nt = 0; nt < 16; nt++) {
            s8 bf = zero_s8();
            if (q < 2) bf = *(const s8*)&Wct[(nt * 16 + l) * 16 + q * 8];
            f4 cz = {0.f, 0.f, 0.f, 0.f};
            acc[nt] = __builtin_amdgcn_mfma_f32_16x16x32_bf16(af, bf, cz, 0, 0, 0);
        }
        // 4: t = acc + pq ; relu ; write u back (bf16) in place
#pragma unroll
        for (int nt = 0; nt < 16; nt++) {
#pragma unroll
            for (int r = 0; r < 4; r++) {
                int er = q * 4 + r, col = nt * 16 + l;
                float t = acc[nt][r] + bf2f(u[er][col]);
                u[er][col] = f2bf(fmaxf(t, 0.f));
            }
        }
        // 5: out = u @ We2 (M=16 edges, N=16, K=256)
        f4 acc2 = {0.f, 0.f, 0.f, 0.f};
#pragma unroll
        for (int ks = 0; ks < 8; ks++) {
            s8 uf = *(const s8*)&u[l][ks * 32 + q * 8];
            s8 wf = *(const s8*)&We2t[(size_t)l * DIM_H + ks * 32 + q * 8];
            acc2 = __builtin_amdgcn_mfma_f32_16x16x32_bf16(uf, wf, acc2, 0, 0, 0);
        }
        // 6: store (row=edge q*4+r, col=l)
#pragma unroll
        for (int r = 0; r < 4; r++) {
            int e = e0 + q * 4 + r;
            outp[(size_t)e * DIM_A + l] = acc2[r] + be2v;
        }
    }
}

extern "C" void kernel_launch(void* const* d_in, const int* in_sizes, int n_in,
                              void* d_out, int out_size, void* d_ws, size_t ws_size,
                              hipStream_t stream) {
    (void)in_sizes; (void)n_in; (void)out_size; (void)ws_size;
    const float* x    = (const float*)d_in[0];
    const int*   ei   = (const int*)d_in[1];
    const float* attr = (const float*)d_in[2];
    const float* W1   = (const float*)d_in[3];
    const float* b1   = (const float*)d_in[4];
    const float* W2   = (const float*)d_in[5];
    const float* b2   = (const float*)d_in[6];
    const float* Wo1  = (const float*)d_in[7];
    const float* bo1  = (const float*)d_in[8];
    const float* Wo2  = (const float*)d_in[9];
    const float* bo2  = (const float*)d_in[10];
    const float* We1  = (const float*)d_in[11];
    const float* be1  = (const float*)d_in[12];
    const float* We2  = (const float*)d_in[13];
    const float* be2  = (const float*)d_in[14];
    const int* rowi = ei;
    const int* coli = ei + N_EDGES;

    float* hout = (float*)d_out;                       // [N][128]
    float* eout = hout + (size_t)N_NODES * DIM_D;      // [E][16]

    char* ws = (char*)d_ws;
    size_t off = 0;
    auto nxt = [&](size_t b) -> void* {
        void* p = ws + off; off = (off + b + 255) & ~(size_t)255; return p;
    };
    float* dinv = (float*)nxt((size_t)N_NODES * 4);
    int* cnt    = (int*)nxt((size_t)N_NODES * 4);
    int* startp = (int*)nxt((size_t)(N_NODES + 1) * 4);
    int* cursor = (int*)nxt((size_t)N_NODES * 4);
    int2* pack  = (int2*)nxt((size_t)N_EDGES * 8);
    u16* W1t  = (u16*)nxt(128 * 256 * 2);
    u16* W2t  = (u16*)nxt(128 * 256 * 2);
    u16* Wo1t = (u16*)nxt(128 * 256 * 2);
    u16* Wo2t = (u16*)nxt(128 * 256 * 2);
    u16* Wat  = (u16*)nxt(128 * 256 * 2);
    u16* Wbt  = (u16*)nxt(128 * 256 * 2);
    u16* Wct  = (u16*)nxt(256 * 16 * 2);
    u16* We2t = (u16*)nxt(16 * 256 * 2);
    float* z  = (float*)nxt((size_t)N_NODES * DIM_D * 4);   // Âx / Ây accumulator (fp32)
    u16* h1   = (u16*)nxt((size_t)N_NODES * DIM_H * 2);     // reused: h1 -> h3 -> P
    u16* yb   = (u16*)nxt((size_t)N_NODES * DIM_D * 2);
    u16* Qb   = (u16*)nxt((size_t)N_NODES * DIM_H * 2);
    // total ws use: ~98 MB

    const int gN = (N_NODES + 255) / 256;
    const int gE = (N_EDGES + 255) / 256;

    // weight transposes (bf16)
    k_twt<<<(128 * 256 + 255) / 256, 256, 0, stream>>>(W1, W1t, 128, 256);
    k_twt<<<(128 * 256 + 255) / 256, 256, 0, stream>>>(W2, W2t, 256, 128);
    k_twt<<<(128 * 256 + 255) / 256, 256, 0, stream>>>(Wo1, Wo1t, 128, 256);
    k_twt<<<(128 * 256 + 255) / 256, 256, 0, stream>>>(Wo2, Wo2t, 256, 128);
    k_twt<<<(128 * 256 + 255) / 256, 256, 0, stream>>>(We1, Wat, 128, 256);
    k_twt<<<(128 * 256 + 255) / 256, 256, 0, stream>>>(We1 + 128 * 256, Wbt, 128, 256);
    k_twt<<<(16 * 256 + 255) / 256, 256, 0, stream>>>(We1 + 256 * 256, Wct, 16, 256);
    k_twt<<<(16 * 256 + 255) / 256, 256, 0, stream>>>(We2, We2t, 256, 16);

    // ---- CSR build (once; reused by both gather layers) ----
    k_zero<<<gN, 256, 0, stream>>>(cnt);
    k_count<<<gE, 256, 0, stream>>>(coli, cnt);
    k_dinv<<<gN, 256, 0, stream>>>(cnt, dinv);
    k_scan<<<1, 1024, 0, stream>>>(cnt, startp);
    k_copy<<<gN, 256, 0, stream>>>(startp, cursor);
    k_fill<<<gE, 256, 0, stream>>>(rowi, coli, dinv, cursor, pack);

    dim3 g4(391, 4), g2(391, 2);
    const int gG = (N_NODES + 3) / 4;   // 4 nodes (waves) per block
    // layer 1: z = Âx ; h1 = relu(z@W1 + b1)
    k_gather<false><<<gG, 256, 0, stream>>>(x, pack, startp, dinv, z);
    k_gemm<false, false, true, true><<<g4, 256, 0, stream>>>(z, W1t, nullptr, b1, h1, N_NODES, 128, 256);
    // layer 2: y = h1@W2 ; z = Ây ; h2 = relu(z + b2) fused into next GEMM's A-stage
    k_gemm<true, false, false, true><<<g2, 256, 0, stream>>>(h1, W2t, nullptr, nullptr, yb, N_NODES, 256, 128);
    k_gather<true><<<gG, 256, 0, stream>>>(yb, pack, startp, dinv, z);
    // output MLP: h3 = relu(relu(z+b2)@Wo1 + bo1) ; h = h3@Wo2 + bo2 -> d_out (fp32)
    k_gemm<false, true, true, true><<<g4, 256, 0, stream>>>(z, Wo1t, b2, bo1, h1, N_NODES, 128, 256);
    k_gemm<true, false, false, false><<<g2, 256, 0, stream>>>(h1, Wo2t, nullptr, bo2, hout, N_NODES, 256, 128);
    // edge predictor precompute: P = h@Wa + be1 ; Q = h@Wb (bf16)
    k_gemm<false, false, false, true><<<g4, 256, 0, stream>>>(hout, Wat, nullptr, be1, h1, N_NODES, 128, 256);
    k_gemm<false, false, false, true><<<g4, 256, 0, stream>>>(hout, Wbt, nullptr, nullptr, Qb, N_NODES, 128, 256);
    // per-edge: out = relu(P[r]+Q[c]+attr@Wc)@We2 + be2
    k_edge<<<1024, 256, 0, stream>>>(h1, Qb, attr, rowi, coli, Wct, We2t, be2, eout);
}

// Round 3
// 750.431 us; speedup vs baseline: 4.3971x; 1.1319x over previous
//
#include <hip/hip_runtime.h>
#include <hip/hip_bf16.h>

// Problem constants (from reference): N=50000, E=800000, D=128, H=256, A=16
#define N_NODES 50000
#define N_EDGES 800000
#define DIM_D   128
#define DIM_H   256
#define DIM_A   16

typedef unsigned short u16;
typedef __attribute__((ext_vector_type(4))) float f4;
typedef __attribute__((ext_vector_type(8))) short s8;

__device__ __forceinline__ u16 f2bf(float f) {
    union { float f; unsigned u; } v; v.f = f;
    unsigned r = v.u + 0x7FFFu + ((v.u >> 16) & 1u);   // RNE
    return (u16)(r >> 16);
}
__device__ __forceinline__ float bf2f(u16 s) {
    union { unsigned u; float f; } v; v.u = ((unsigned)s) << 16; return v.f;
}
__device__ __forceinline__ s8 zero_s8() {
    s8 v;
#pragma unroll
    for (int i = 0; i < 8; i++) v[i] = 0;
    return v;
}

// ---------------- CSR build ----------------
__global__ __launch_bounds__(256) void k_zero(int* __restrict__ cnt) {
    int i = blockIdx.x * 256 + threadIdx.x;
    if (i < N_NODES) cnt[i] = 0;
}
__global__ __launch_bounds__(256) void k_count(const int* __restrict__ coli, int* __restrict__ cnt) {
    int e = blockIdx.x * 256 + threadIdx.x;
    if (e < N_EDGES) atomicAdd(&cnt[coli[e]], 1);
}
__global__ __launch_bounds__(256) void k_dinv(const int* __restrict__ cnt, float* __restrict__ dinv) {
    int i = blockIdx.x * 256 + threadIdx.x;
    if (i < N_NODES) dinv[i] = rsqrtf((float)(cnt[i] + 1));   // +1 self-loop
}

#define SCAN_C 49   // 1024 * 49 = 50176 >= N_NODES
__global__ __launch_bounds__(1024) void k_scan(const int* __restrict__ cnt, int* __restrict__ start) {
    __shared__ int ps[1024];
    int t = threadIdx.x;
    int base = t * SCAN_C;
    int sum = 0;
    for (int i = 0; i < SCAN_C; i++) {
        int idx = base + i;
        sum += (idx < N_NODES) ? cnt[idx] : 0;
    }
    ps[t] = sum;
    __syncthreads();
    for (int ofs = 1; ofs < 1024; ofs <<= 1) {
        int v = (t >= ofs) ? ps[t - ofs] : 0;
        __syncthreads();
        ps[t] += v;
        __syncthreads();
    }
    int run = (t > 0) ? ps[t - 1] : 0;
    for (int i = 0; i < SCAN_C; i++) {
        int idx = base + i;
        if (idx < N_NODES) {
            start[idx] = run;
            run += cnt[idx];
        }
    }
    if (t == 1023) start[N_NODES] = ps[1023];
}
__global__ __launch_bounds__(256) void k_copy(const int* __restrict__ start, int* __restrict__ cursor) {
    int i = blockIdx.x * 256 + threadIdx.x;
    if (i < N_NODES) cursor[i] = start[i];
}
// pack[slot] = {src_node, dinv[src]*dinv[dst]} bucketed by destination
__global__ __launch_bounds__(256) void k_fill(const int* __restrict__ rowi, const int* __restrict__ coli,
                                              const float* __restrict__ dinv,
                                              int* __restrict__ cursor, int2* __restrict__ pack) {
    int e = blockIdx.x * 256 + threadIdx.x;
    if (e >= N_EDGES) return;
    int r = rowi[e], c = coli[e];
    int slot = atomicAdd(&cursor[c], 1);
    float w = dinv[r] * dinv[c];
    pack[slot] = make_int2(r, __float_as_int(w));
}

// ---------------- CSR gather: z[n] = X[n]*dinv[n]^2 + sum_{e->n} X[src]*w ----------------
// one wave per node; two 32-lane halves process alternate CSR entries, lane covers 4 cols
template <bool SRC_BF16>
__global__ __launch_bounds__(256) void k_gather(const void* __restrict__ X,
                                                const int2* __restrict__ pack,
                                                const int* __restrict__ start,
                                                const float* __restrict__ dinv,
                                                float* __restrict__ z) {
    int node = blockIdx.x * 4 + (threadIdx.x >> 6);
    if (node >= N_NODES) return;
    int lane = threadIdx.x & 63;
    int half = lane >> 5, j = lane & 31;
    int c4 = j * 4;
    float di = dinv[node];
    f4 acc = {0.f, 0.f, 0.f, 0.f};
    if (half == 0) {
        float sl = di * di;
        if (SRC_BF16) {
            ushort4 u = *(const ushort4*)&((const u16*)X)[(size_t)node * DIM_D + c4];
            acc[0] = bf2f(u.x) * sl; acc[1] = bf2f(u.y) * sl;
            acc[2] = bf2f(u.z) * sl; acc[3] = bf2f(u.w) * sl;
        } else {
            float4 v = *(const float4*)&((const float*)X)[(size_t)node * DIM_D + c4];
            acc[0] = v.x * sl; acc[1] = v.y * sl; acc[2] = v.z * sl; acc[3] = v.w * sl;
        }
    }
    int s = start[node], e = start[node + 1];
#pragma unroll 2
    for (int i = s + half; i < e; i += 2) {
        int2 p = pack[i];
        float w = __int_as_float(p.y);
        if (SRC_BF16) {
            ushort4 u = *(const ushort4*)&((const u16*)X)[(size_t)p.x * DIM_D + c4];
            acc[0] += bf2f(u.x) * w; acc[1] += bf2f(u.y) * w;
            acc[2] += bf2f(u.z) * w; acc[3] += bf2f(u.w) * w;
        } else {
            float4 v = *(const float4*)&((const float*)X)[(size_t)p.x * DIM_D + c4];
            acc[0] += v.x * w; acc[1] += v.y * w; acc[2] += v.z * w; acc[3] += v.w * w;
        }
    }
    // combine halves: lane j (<32) += lane j+32
    float t0 = acc[0] + __shfl(acc[0], j + 32);
    float t1 = acc[1] + __shfl(acc[1], j + 32);
    float t2 = acc[2] + __shfl(acc[2], j + 32);
    float t3 = acc[3] + __shfl(acc[3], j + 32);
    if (half == 0)
        *(float4*)&z[(size_t)node * DIM_D + c4] = make_float4(t0, t1, t2, t3);
}

// ---------------- weight transpose+cast: W[K][Nn] fp32 -> Wt[Nn][K] bf16 ----------------
__global__ __launch_bounds__(256) void k_twt(const float* __restrict__ W, u16* __restrict__ Wt,
                                             int K, int Nn) {
    int idx = blockIdx.x * 256 + threadIdx.x;
    if (idx >= K * Nn) return;
    int k = idx / Nn, n = idx - k * Nn;
    Wt[n * K + k] = f2bf(W[idx]);
}

// combined edge-predictor bias: bpq[0..255]=be1, bpq[256..511]=0
__global__ __launch_bounds__(256) void k_bpq(const float* __restrict__ be1, float* __restrict__ bpq) {
    int i = blockIdx.x * 256 + threadIdx.x;
    if (i < 512) bpq[i] = (i < 256) ? be1[i] : 0.f;
}

// ---------------- MFMA GEMM: C[M][Nn] = post(A[M][K] @ W + postB), W given as Wt[Nn][K] bf16 ----
// A_BF16: A is bf16[M][K] else fp32. PRE_BR: A' = relu(A + preB[k]) before cast.
#define BM 128
#define BN 64
#define BK 32
#define BKP 56   // padded K stride in LDS (bf16 elems); 112B rows -> ~2-way banks, 16B aligned

template <bool A_BF16, bool PRE_BR, bool POST_RELU, bool OUT_BF16>
__global__ __launch_bounds__(256) void k_gemm(const void* __restrict__ Ap,
                                              const u16* __restrict__ Wt,
                                              const float* __restrict__ preB,
                                              const float* __restrict__ postB,
                                              void* __restrict__ Cp,
                                              int M, int K, int Nn) {
    __shared__ __align__(16) u16 As[BM * BKP];
    __shared__ __align__(16) u16 Bs[BN * BKP];
    const int tid = threadIdx.x;
    const int wid = tid >> 6, lane = tid & 63;
    const int q = lane >> 4, l = lane & 15;
    const int bm = blockIdx.x * BM, bn = blockIdx.y * BN;

    f4 acc[8];
#pragma unroll
    for (int i = 0; i < 8; i++) { f4 zz = {0.f, 0.f, 0.f, 0.f}; acc[i] = zz; }

    for (int k0 = 0; k0 < K; k0 += BK) {
        __syncthreads();
        // stage W tile: Bs[n][k], n in [bn,bn+64), k in [k0,k0+32)
        {
            int n = tid >> 2, kc = (tid & 3) * 8;
            *(int4*)&Bs[n * BKP + kc] = *(const int4*)&Wt[(size_t)(bn + n) * K + k0 + kc];
        }
        // stage A tile: As[m][k]
        if (A_BF16) {
            const u16* A = (const u16*)Ap;
#pragma unroll
            for (int p = 0; p < 2; p++) {
                int m = (tid >> 2) + p * 64, kc = (tid & 3) * 8;
                int gm = bm + m; if (gm >= M) gm = M - 1;
                *(int4*)&As[m * BKP + kc] = *(const int4*)&A[(size_t)gm * K + k0 + kc];
            }
        } else {
            const float* A = (const float*)Ap;
#pragma unroll
            for (int p = 0; p < 4; p++) {
                int m = (tid >> 3) + p * 32, k4 = (tid & 7) * 4;
                int gm = bm + m; if (gm >= M) gm = M - 1;
                float4 v = *(const float4*)&A[(size_t)gm * K + k0 + k4];
                if (PRE_BR) {
                    const float4 pb = *(const float4*)&preB[k0 + k4];
                    v.x = fmaxf(v.x + pb.x, 0.f);
                    v.y = fmaxf(v.y + pb.y, 0.f);
                    v.z = fmaxf(v.z + pb.z, 0.f);
                    v.w = fmaxf(v.w + pb.w, 0.f);
                }
                ushort4 o;
                o.x = f2bf(v.x); o.y = f2bf(v.y); o.z = f2bf(v.z); o.w = f2bf(v.w);
                *(ushort4*)&As[m * BKP + k4] = o;
            }
        }
        __syncthreads();

        s8 af[2], bf[4];
#pragma unroll
        for (int mt = 0; mt < 2; mt++)
            af[mt] = *(const s8*)&As[(wid * 32 + mt * 16 + l) * BKP + q * 8];
#pragma unroll
        for (int nt = 0; nt < 4; nt++)
            bf[nt] = *(const s8*)&Bs[(nt * 16 + l) * BKP + q * 8];
#pragma unroll
        for (int mt = 0; mt < 2; mt++)
#pragma unroll
            for (int nt = 0; nt < 4; nt++)
                acc[mt * 4 + nt] = __builtin_amdgcn_mfma_f32_16x16x32_bf16(
                    af[mt], bf[nt], acc[mt * 4 + nt], 0, 0, 0);
    }

    // epilogue: C row = q*4+r, col = l (per 16x16 tile)
#pragma unroll
    for (int mt = 0; mt < 2; mt++) {
#pragma unroll
        for (int nt = 0; nt < 4; nt++) {
            int colg = bn + nt * 16 + l;
            float pb = postB ? postB[colg] : 0.0f;
#pragma unroll
            for (int r = 0; r < 4; r++) {
                int rowg = bm + wid * 32 + mt * 16 + q * 4 + r;
                if (rowg < M) {
                    float v = acc[mt * 4 + nt][r] + pb;
                    if (POST_RELU) v = fmaxf(v, 0.f);
                    if (OUT_BF16)
                        ((u16*)Cp)[(size_t)rowg * Nn + colg] = f2bf(v);
                    else
                        ((float*)Cp)[(size_t)rowg * Nn + colg] = v;
                }
            }
        }
    }
}

// ---------------- edge predictor: 16 edges per wave -----------------------------------------
// MFMA-1 computes D[m=hidden][n=edge] so lane (q,l) holds edge l, cols mt*16+q*4+r -> the
// P/Q gather lands directly in C-layout registers (no LDS round-trip, no scalar fix-up).
// u (bf16, row-major per edge) goes to LDS via one ds_write_b64 per mt; MFMA-2 reads b128.
__global__ __launch_bounds__(256) void k_edge(const u16* __restrict__ PQ,     // [N][512]: P|Q
                                              const float* __restrict__ attr,
                                              const int* __restrict__ rowi,
                                              const int* __restrict__ coli,
                                              const u16* __restrict__ Wct,    // [256][16] bf16
                                              const u16* __restrict__ We2t,   // [16][256] bf16
                                              const float* __restrict__ be2,
                                              float* __restrict__ outp) {
    __shared__ __align__(16) u16 ub[4][16][272];   // per-wave u tile, padded rows
    const int tid = threadIdx.x, wid = tid >> 6, lane = tid & 63;
    const int q = lane >> 4, l = lane & 15;
    const float be2v = be2[l];
    u16(*u)[272] = ub[wid];

    // tile-invariant Wc A-fragments: A[m=c_off=l][k=q*8+j] = Wct[mt*16+l][k], k<16
    s8 wcf[16];
#pragma unroll
    for (int mt = 0; mt < 16; mt++) {
        wcf[mt] = zero_s8();
        if (q < 2) wcf[mt] = *(const s8*)&Wct[(mt * 16 + l) * 16 + q * 8];
    }

    for (int tile = blockIdx.x * 4 + wid; tile < N_EDGES / 16; tile += gridDim.x * 4) {
        const int e0 = tile * 16;
        const int re = rowi[e0 + l], ce = coli[e0 + l];
        const u16* prow = PQ + (size_t)re * 512 + q * 4;          // P half
        const u16* qrow = PQ + (size_t)ce * 512 + 256 + q * 4;    // Q half

        // attr B-frag: B[k=q*8+j][n=edge=l], K=16 padded to 32 with zeros
        s8 af = zero_s8();
        if (q < 2) {
            const float* ap = &attr[(size_t)(e0 + l) * DIM_A + q * 8];
            float4 a0 = *(const float4*)ap;
            float4 a1 = *(const float4*)(ap + 4);
            af[0] = (short)f2bf(a0.x); af[1] = (short)f2bf(a0.y);
            af[2] = (short)f2bf(a0.z); af[3] = (short)f2bf(a0.w);
            af[4] = (short)f2bf(a1.x); af[5] = (short)f2bf(a1.y);
            af[6] = (short)f2bf(a1.z); af[7] = (short)f2bf(a1.w);
        }

        // fused: MFMA-1 (attr@Wc, transposed roles) + register-resident P/Q gather + relu + pack
#pragma unroll
        for (int mt = 0; mt < 16; mt++) {
            f4 cz = {0.f, 0.f, 0.f, 0.f};
            f4 acc = __builtin_amdgcn_mfma_f32_16x16x32_bf16(wcf[mt], af, cz, 0, 0, 0);
            ushort4 pu = *(const ushort4*)(prow + mt * 16);
            ushort4 qu = *(const ushort4*)(qrow + mt * 16);
            float t0 = bf2f(pu.x) + bf2f(qu.x) + acc[0];
            float t1 = bf2f(pu.y) + bf2f(qu.y) + acc[1];
            float t2 = bf2f(pu.z) + bf2f(qu.z) + acc[2];
            float t3 = bf2f(pu.w) + bf2f(qu.w) + acc[3];
            ushort4 o;
            o.x = f2bf(fmaxf(t0, 0.f)); o.y = f2bf(fmaxf(t1, 0.f));
            o.z = f2bf(fmaxf(t2, 0.f)); o.w = f2bf(fmaxf(t3, 0.f));
            *(ushort4*)&u[l][mt * 16 + q * 4] = o;   // b64, 4 dwords/bank inherent, conflict-free
        }

        // MFMA-2: out[16 edges][16] = u @ We2, K=256
        f4 acc2 = {0.f, 0.f, 0.f, 0.f};
#pragma unroll
        for (int ks = 0; ks < 8; ks++) {
            s8 uf = *(const s8*)&u[l][ks * 32 + q * 8];
            s8 wf = *(const s8*)&We2t[(size_t)l * DIM_H + ks * 32 + q * 8];
            acc2 = __builtin_amdgcn_mfma_f32_16x16x32_bf16(uf, wf, acc2, 0, 0, 0);
        }
#pragma unroll
        for (int r = 0; r < 4; r++) {
            int e = e0 + q * 4 + r;
            outp[(size_t)e * DIM_A + l] = acc2[r] + be2v;
        }
    }
}

extern "C" void kernel_launch(void* const* d_in, const int* in_sizes, int n_in,
                              void* d_out, int out_size, void* d_ws, size_t ws_size,
                              hipStream_t stream) {
    (void)in_sizes; (void)n_in; (void)out_size; (void)ws_size;
    const float* x    = (const float*)d_in[0];
    const int*   ei   = (const int*)d_in[1];
    const float* attr = (const float*)d_in[2];
    const float* W1   = (const float*)d_in[3];
    const float* b1   = (const float*)d_in[4];
    const float* W2   = (const float*)d_in[5];
    const float* b2   = (const float*)d_in[6];
    const float* Wo1  = (const float*)d_in[7];
    const float* bo1  = (const float*)d_in[8];
    const float* Wo2  = (const float*)d_in[9];
    const float* bo2  = (const float*)d_in[10];
    const float* We1  = (const float*)d_in[11];
    const float* be1  = (const float*)d_in[12];
    const float* We2  = (const float*)d_in[13];
    const float* be2  = (const float*)d_in[14];
    const int* rowi = ei;
    const int* coli = ei + N_EDGES;

    float* hout = (float*)d_out;                       // [N][128]
    float* eout = hout + (size_t)N_NODES * DIM_D;      // [E][16]

    char* ws = (char*)d_ws;
    size_t off = 0;
    auto nxt = [&](size_t b) -> void* {
        void* p = ws + off; off = (off + b + 255) & ~(size_t)255; return p;
    };
    float* dinv = (float*)nxt((size_t)N_NODES * 4);
    int* cnt    = (int*)nxt((size_t)N_NODES * 4);
    int* startp = (int*)nxt((size_t)(N_NODES + 1) * 4);
    int* cursor = (int*)nxt((size_t)N_NODES * 4);
    int2* pack  = (int2*)nxt((size_t)N_EDGES * 8);
    u16* W1t   = (u16*)nxt(128 * 256 * 2);
    u16* W2t   = (u16*)nxt(128 * 256 * 2);
    u16* Wo1t  = (u16*)nxt(128 * 256 * 2);
    u16* Wo2t  = (u16*)nxt(128 * 256 * 2);
    u16* Wabt  = (u16*)nxt(512 * 128 * 2);   // [512][128]: Wa^T | Wb^T
    u16* Wct   = (u16*)nxt(256 * 16 * 2);
    u16* We2t  = (u16*)nxt(16 * 256 * 2);
    float* bpq = (float*)nxt(512 * 4);
    float* z   = (float*)nxt((size_t)N_NODES * DIM_D * 4);   // Âx / Ây accumulator (fp32)
    u16* h1    = (u16*)nxt((size_t)N_NODES * DIM_H * 2);     // intermediate [N][256]
    u16* yb    = (u16*)nxt((size_t)N_NODES * DIM_D * 2);
    // PQ [N][512] bf16 (51.2 MB) overlays z+h1 (both dead once hout is computed)
    u16* PQb = (u16*)z;

    const int gN = (N_NODES + 255) / 256;
    const int gE = (N_EDGES + 255) / 256;

    // weight transposes (bf16)
    k_twt<<<(128 * 256 + 255) / 256, 256, 0, stream>>>(W1, W1t, 128, 256);
    k_twt<<<(128 * 256 + 255) / 256, 256, 0, stream>>>(W2, W2t, 256, 128);
    k_twt<<<(128 * 256 + 255) / 256, 256, 0, stream>>>(Wo1, Wo1t, 128, 256);
    k_twt<<<(128 * 256 + 255) / 256, 256, 0, stream>>>(Wo2, Wo2t, 256, 128);
    k_twt<<<(128 * 256 + 255) / 256, 256, 0, stream>>>(We1, Wabt, 128, 256);
    k_twt<<<(128 * 256 + 255) / 256, 256, 0, stream>>>(We1 + 128 * 256, Wabt + 256 * 128, 128, 256);
    k_twt<<<(16 * 256 + 255) / 256, 256, 0, stream>>>(We1 + 256 * 256, Wct, 16, 256);
    k_twt<<<(16 * 256 + 255) / 256, 256, 0, stream>>>(We2, We2t, 256, 16);
    k_bpq<<<2, 256, 0, stream>>>(be1, bpq);

    // ---- CSR build (once; reused by both gather layers) ----
    k_zero<<<gN, 256, 0, stream>>>(cnt);
    k_count<<<gE, 256, 0, stream>>>(coli, cnt);
    k_dinv<<<gN, 256, 0, stream>>>(cnt, dinv);
    k_scan<<<1, 1024, 0, stream>>>(cnt, startp);
    k_copy<<<gN, 256, 0, stream>>>(startp, cursor);
    k_fill<<<gE, 256, 0, stream>>>(rowi, coli, dinv, cursor, pack);

    dim3 g4(391, 4), g2(391, 2), g8(391, 8);
    const int gG = (N_NODES + 3) / 4;   // 4 nodes (waves) per block
    // layer 1: z = Âx ; h1 = relu(z@W1 + b1)
    k_gather<false><<<gG, 256, 0, stream>>>(x, pack, startp, dinv, z);
    k_gemm<false, false, true, true><<<g4, 256, 0, stream>>>(z, W1t, nullptr, b1, h1, N_NODES, 128, 256);
    // layer 2: y = h1@W2 ; z = Ây ; h2 = relu(z + b2) fused into next GEMM's A-stage
    k_gemm<true, false, false, true><<<g2, 256, 0, stream>>>(h1, W2t, nullptr, nullptr, yb, N_NODES, 256, 128);
    k_gather<true><<<gG, 256, 0, stream>>>(yb, pack, startp, dinv, z);
    // output MLP: h3 = relu(relu(z+b2)@Wo1 + bo1) ; h = h3@Wo2 + bo2 -> d_out (fp32)
    k_gemm<false, true, true, true><<<g4, 256, 0, stream>>>(z, Wo1t, b2, bo1, h1, N_NODES, 128, 256);
    k_gemm<true, false, false, false><<<g2, 256, 0, stream>>>(h1, Wo2t, nullptr, bo2, hout, N_NODES, 256, 128);
    // edge predictor precompute (single fused GEMM): PQ = [h@Wa + be1 | h@Wb]  (bf16, [N][512])
    k_gemm<false, false, false, true><<<g8, 256, 0, stream>>>(hout, Wabt, nullptr, bpq, PQb, N_NODES, 128, 512);
    // per-edge: out = relu(P[r]+Q[c]+attr@Wc)@We2 + be2
    k_edge<<<1024, 256, 0, stream>>>(PQb, attr, rowi, coli, Wct, We2t, be2, eout);
}

// Round 4
// 738.741 us; speedup vs baseline: 4.4667x; 1.0158x over previous
//
#include <hip/hip_runtime.h>
#include <hip/hip_bf16.h>

// Problem constants (from reference): N=50000, E=800000, D=128, H=256, A=16
#define N_NODES 50000
#define N_EDGES 800000
#define DIM_D   128
#define DIM_H   256
#define DIM_A   16

typedef unsigned short u16;
typedef __attribute__((ext_vector_type(4))) float f4;
typedef __attribute__((ext_vector_type(8))) short s8;
typedef __attribute__((ext_vector_type(4))) short s4;

__device__ __forceinline__ u16 f2bf(float f) {
    union { float f; unsigned u; } v; v.f = f;
    unsigned r = v.u + 0x7FFFu + ((v.u >> 16) & 1u);   // RNE
    return (u16)(r >> 16);
}
__device__ __forceinline__ float bf2f(u16 s) {
    union { unsigned u; float f; } v; v.u = ((unsigned)s) << 16; return v.f;
}
__device__ __forceinline__ s8 zero_s8() {
    s8 v;
#pragma unroll
    for (int i = 0; i < 8; i++) v[i] = 0;
    return v;
}

// ---------------- CSR build ----------------
__global__ __launch_bounds__(256) void k_zero(int* __restrict__ cnt) {
    int i = blockIdx.x * 256 + threadIdx.x;
    if (i < N_NODES) cnt[i] = 0;
}
__global__ __launch_bounds__(256) void k_count(const int* __restrict__ coli, int* __restrict__ cnt) {
    int e = blockIdx.x * 256 + threadIdx.x;
    if (e < N_EDGES) atomicAdd(&cnt[coli[e]], 1);
}
__global__ __launch_bounds__(256) void k_dinv(const int* __restrict__ cnt, float* __restrict__ dinv) {
    int i = blockIdx.x * 256 + threadIdx.x;
    if (i < N_NODES) dinv[i] = rsqrtf((float)(cnt[i] + 1));   // +1 self-loop
}

#define SCAN_C 49   // 1024 * 49 = 50176 >= N_NODES
__global__ __launch_bounds__(1024) void k_scan(const int* __restrict__ cnt, int* __restrict__ start) {
    __shared__ int ps[1024];
    int t = threadIdx.x;
    int base = t * SCAN_C;
    int sum = 0;
    for (int i = 0; i < SCAN_C; i++) {
        int idx = base + i;
        sum += (idx < N_NODES) ? cnt[idx] : 0;
    }
    ps[t] = sum;
    __syncthreads();
    for (int ofs = 1; ofs < 1024; ofs <<= 1) {
        int v = (t >= ofs) ? ps[t - ofs] : 0;
        __syncthreads();
        ps[t] += v;
        __syncthreads();
    }
    int run = (t > 0) ? ps[t - 1] : 0;
    for (int i = 0; i < SCAN_C; i++) {
        int idx = base + i;
        if (idx < N_NODES) {
            start[idx] = run;
            run += cnt[idx];
        }
    }
    if (t == 1023) start[N_NODES] = ps[1023];
}
__global__ __launch_bounds__(256) void k_copy(const int* __restrict__ start, int* __restrict__ cursor) {
    int i = blockIdx.x * 256 + threadIdx.x;
    if (i < N_NODES) cursor[i] = start[i];
}
// pack[slot] = {src_node, dinv[src]*dinv[dst]} bucketed by destination
__global__ __launch_bounds__(256) void k_fill(const int* __restrict__ rowi, const int* __restrict__ coli,
                                              const float* __restrict__ dinv,
                                              int* __restrict__ cursor, int2* __restrict__ pack) {
    int e = blockIdx.x * 256 + threadIdx.x;
    if (e >= N_EDGES) return;
    int r = rowi[e], c = coli[e];
    int slot = atomicAdd(&cursor[c], 1);
    float w = dinv[r] * dinv[c];
    pack[slot] = make_int2(r, __float_as_int(w));
}

// ---------------- fp32 -> bf16 cast (x table) ----------------
__global__ __launch_bounds__(256) void k_cast(const float* __restrict__ X, u16* __restrict__ Y, int n4) {
    int i = blockIdx.x * 256 + threadIdx.x;
    if (i >= n4) return;
    float4 v = *(const float4*)&X[(size_t)i * 4];
    ushort4 o;
    o.x = f2bf(v.x); o.y = f2bf(v.y); o.z = f2bf(v.z); o.w = f2bf(v.w);
    *(ushort4*)&Y[(size_t)i * 4] = o;
}

// ---------------- CSR gather: z[n] = X[n]*dinv[n]^2 + sum_{e->n} X[src]*w ----------------
// one wave per node; two 32-lane halves process alternate CSR entries, lane covers 4 cols (bf16 X)
__global__ __launch_bounds__(256) void k_gather(const u16* __restrict__ X,
                                                const int2* __restrict__ pack,
                                                const int* __restrict__ start,
                                                const float* __restrict__ dinv,
                                                float* __restrict__ z) {
    int node = blockIdx.x * 4 + (threadIdx.x >> 6);
    if (node >= N_NODES) return;
    int lane = threadIdx.x & 63;
    int half = lane >> 5, j = lane & 31;
    int c4 = j * 4;
    float di = dinv[node];
    f4 acc = {0.f, 0.f, 0.f, 0.f};
    if (half == 0) {
        float sl = di * di;
        ushort4 u = *(const ushort4*)&X[(size_t)node * DIM_D + c4];
        acc[0] = bf2f(u.x) * sl; acc[1] = bf2f(u.y) * sl;
        acc[2] = bf2f(u.z) * sl; acc[3] = bf2f(u.w) * sl;
    }
    int s = start[node], e = start[node + 1];
#pragma unroll 4
    for (int i = s + half; i < e; i += 2) {
        int2 p = pack[i];
        float w = __int_as_float(p.y);
        ushort4 u = *(const ushort4*)&X[(size_t)p.x * DIM_D + c4];
        acc[0] += bf2f(u.x) * w; acc[1] += bf2f(u.y) * w;
        acc[2] += bf2f(u.z) * w; acc[3] += bf2f(u.w) * w;
    }
    // combine halves: lane j (<32) += lane j+32
    float t0 = acc[0] + __shfl(acc[0], j + 32);
    float t1 = acc[1] + __shfl(acc[1], j + 32);
    float t2 = acc[2] + __shfl(acc[2], j + 32);
    float t3 = acc[3] + __shfl(acc[3], j + 32);
    if (half == 0)
        *(float4*)&z[(size_t)node * DIM_D + c4] = make_float4(t0, t1, t2, t3);
}

// ---------------- weight transpose+cast: W[K][Nn] fp32 -> Wt[Nn][K] bf16 ----------------
__global__ __launch_bounds__(256) void k_twt(const float* __restrict__ W, u16* __restrict__ Wt,
                                             int K, int Nn) {
    int idx = blockIdx.x * 256 + threadIdx.x;
    if (idx >= K * Nn) return;
    int k = idx / Nn, n = idx - k * Nn;
    Wt[n * K + k] = f2bf(W[idx]);
}

// combined edge-predictor bias: bpq[0..255]=be1, bpq[256..511]=0
__global__ __launch_bounds__(256) void k_bpq(const float* __restrict__ be1, float* __restrict__ bpq) {
    int i = blockIdx.x * 256 + threadIdx.x;
    if (i < 512) bpq[i] = (i < 256) ? be1[i] : 0.f;
}

// ---------------- MFMA GEMM: C[M][Nn] = post(A[M][K] @ W + postB), W given as Wt[Nn][K] bf16 ----
// A_BF16: A is bf16[M][K] else fp32. PRE_BR: A' = relu(A + preB[k]) before cast.
#define BM 128
#define BN 64
#define BK 32
#define BKP 56   // padded K stride in LDS (bf16 elems)

template <bool A_BF16, bool PRE_BR, bool POST_RELU, bool OUT_BF16>
__global__ __launch_bounds__(256) void k_gemm(const void* __restrict__ Ap,
                                              const u16* __restrict__ Wt,
                                              const float* __restrict__ preB,
                                              const float* __restrict__ postB,
                                              void* __restrict__ Cp,
                                              int M, int K, int Nn) {
    __shared__ __align__(16) u16 As[BM * BKP];
    __shared__ __align__(16) u16 Bs[BN * BKP];
    const int tid = threadIdx.x;
    const int wid = tid >> 6, lane = tid & 63;
    const int q = lane >> 4, l = lane & 15;
    const int bm = blockIdx.x * BM, bn = blockIdx.y * BN;

    f4 acc[8];
#pragma unroll
    for (int i = 0; i < 8; i++) { f4 zz = {0.f, 0.f, 0.f, 0.f}; acc[i] = zz; }

    for (int k0 = 0; k0 < K; k0 += BK) {
        __syncthreads();
        // stage W tile: Bs[n][k], n in [bn,bn+64), k in [k0,k0+32)
        {
            int n = tid >> 2, kc = (tid & 3) * 8;
            *(int4*)&Bs[n * BKP + kc] = *(const int4*)&Wt[(size_t)(bn + n) * K + k0 + kc];
        }
        // stage A tile: As[m][k]
        if (A_BF16) {
            const u16* A = (const u16*)Ap;
#pragma unroll
            for (int p = 0; p < 2; p++) {
                int m = (tid >> 2) + p * 64, kc = (tid & 3) * 8;
                int gm = bm + m; if (gm >= M) gm = M - 1;
                *(int4*)&As[m * BKP + kc] = *(const int4*)&A[(size_t)gm * K + k0 + kc];
            }
        } else {
            const float* A = (const float*)Ap;
#pragma unroll
            for (int p = 0; p < 4; p++) {
                int m = (tid >> 3) + p * 32, k4 = (tid & 7) * 4;
                int gm = bm + m; if (gm >= M) gm = M - 1;
                float4 v = *(const float4*)&A[(size_t)gm * K + k0 + k4];
                if (PRE_BR) {
                    const float4 pb = *(const float4*)&preB[k0 + k4];
                    v.x = fmaxf(v.x + pb.x, 0.f);
                    v.y = fmaxf(v.y + pb.y, 0.f);
                    v.z = fmaxf(v.z + pb.z, 0.f);
                    v.w = fmaxf(v.w + pb.w, 0.f);
                }
                ushort4 o;
                o.x = f2bf(v.x); o.y = f2bf(v.y); o.z = f2bf(v.z); o.w = f2bf(v.w);
                *(ushort4*)&As[m * BKP + k4] = o;
            }
        }
        __syncthreads();

        s8 af[2], bf[4];
#pragma unroll
        for (int mt = 0; mt < 2; mt++)
            af[mt] = *(const s8*)&As[(wid * 32 + mt * 16 + l) * BKP + q * 8];
#pragma unroll
        for (int nt = 0; nt < 4; nt++)
            bf[nt] = *(const s8*)&Bs[(nt * 16 + l) * BKP + q * 8];
#pragma unroll
        for (int mt = 0; mt < 2; mt++)
#pragma unroll
            for (int nt = 0; nt < 4; nt++)
                acc[mt * 4 + nt] = __builtin_amdgcn_mfma_f32_16x16x32_bf16(
                    af[mt], bf[nt], acc[mt * 4 + nt], 0, 0, 0);
    }

    // epilogue: C row = q*4+r, col = l (per 16x16 tile)
#pragma unroll
    for (int mt = 0; mt < 2; mt++) {
#pragma unroll
        for (int nt = 0; nt < 4; nt++) {
            int colg = bn + nt * 16 + l;
            float pb = postB ? postB[colg] : 0.0f;
#pragma unroll
            for (int r = 0; r < 4; r++) {
                int rowg = bm + wid * 32 + mt * 16 + q * 4 + r;
                if (rowg < M) {
                    float v = acc[mt * 4 + nt][r] + pb;
                    if (POST_RELU) v = fmaxf(v, 0.f);
                    if (OUT_BF16)
                        ((u16*)Cp)[(size_t)rowg * Nn + colg] = f2bf(v);
                    else
                        ((float*)Cp)[(size_t)rowg * Nn + colg] = v;
                }
            }
        }
    }
}

// ---------------- edge predictor: 16 edges per wave -----------------------------------------
#if __has_builtin(__builtin_amdgcn_mfma_f32_16x16x16bf16_1k)
// LDS-free path. Both matmuls use 16x16x16 MFMA whose A/B frag k-chunk (k=q*4+j) exactly
// matches the C/D row-chunk (row=q*4+r) — so MFMA-1's fused output (P+Q+attr@Wc, relu,
// packed ushort4) feeds MFMA-2 directly as a B-fragment. No LDS, no layout fix-up.
// MFMA-1: D[m=hidden16][n=edge] = Wc^T-slice @ attr^T.  MFMA-2 (transposed, accumulated over
// mt): D[m=outcol][n=edge] = We2^T @ u^T  -> lane (q,l): edge l, outcols q*4+r -> float4 store.
__global__ __launch_bounds__(256) void k_edge(const u16* __restrict__ PQ,     // [N][512]: P|Q
                                              const float* __restrict__ attr,
                                              const int* __restrict__ rowi,
                                              const int* __restrict__ coli,
                                              const u16* __restrict__ Wct,    // [256][16] bf16
                                              const u16* __restrict__ We2t,   // [16][256] bf16
                                              const float* __restrict__ be2,
                                              float* __restrict__ outp) {
    const int tid = threadIdx.x, wid = tid >> 6, lane = tid & 63;
    const int q = lane >> 4, l = lane & 15;
    const float4 be2v = *(const float4*)&be2[q * 4];

    // tile-invariant We2^T A-frags: A[m=outcol=l][k=mt*16+q*4+j]
    s4 we2f[16];
#pragma unroll
    for (int mt = 0; mt < 16; mt++)
        we2f[mt] = *(const s4*)&We2t[(size_t)l * DIM_H + mt * 16 + q * 4];

    for (int tile = blockIdx.x * 4 + wid; tile < N_EDGES / 16; tile += gridDim.x * 4) {
        const int e0 = tile * 16;
        const int re = rowi[e0 + l], ce = coli[e0 + l];
        const u16* prow = PQ + (size_t)re * 512 + q * 4;          // P half
        const u16* qrow = PQ + (size_t)ce * 512 + 256 + q * 4;    // Q half

        // attr B-frag: B[k=q*4+j][n=edge=l]
        float4 av = *(const float4*)&attr[(size_t)(e0 + l) * DIM_A + q * 4];
        s4 af;
        af[0] = (short)f2bf(av.x); af[1] = (short)f2bf(av.y);
        af[2] = (short)f2bf(av.z); af[3] = (short)f2bf(av.w);

        f4 acc2 = {0.f, 0.f, 0.f, 0.f};
#pragma unroll
        for (int mt = 0; mt < 16; mt++) {
            // Wc^T A-frag for this hidden-16 block: A[m=hidden=l][k=attr=q*4+j]
            s4 wcf = *(const s4*)&Wct[(mt * 16 + l) * 16 + q * 4];
            f4 cz = {0.f, 0.f, 0.f, 0.f};
            f4 acc = __builtin_amdgcn_mfma_f32_16x16x16bf16_1k(wcf, af, cz, 0, 0, 0);
            ushort4 pu = *(const ushort4*)(prow + mt * 16);
            ushort4 qu = *(const ushort4*)(qrow + mt * 16);
            float t0 = bf2f(pu.x) + bf2f(qu.x) + acc[0];
            float t1 = bf2f(pu.y) + bf2f(qu.y) + acc[1];
            float t2 = bf2f(pu.z) + bf2f(qu.z) + acc[2];
            float t3 = bf2f(pu.w) + bf2f(qu.w) + acc[3];
            s4 uf;   // B-frag of u^T: lane (q,l) -> edge l, k = mt*16 + q*4 + j
            uf[0] = (short)f2bf(fmaxf(t0, 0.f));
            uf[1] = (short)f2bf(fmaxf(t1, 0.f));
            uf[2] = (short)f2bf(fmaxf(t2, 0.f));
            uf[3] = (short)f2bf(fmaxf(t3, 0.f));
            acc2 = __builtin_amdgcn_mfma_f32_16x16x16bf16_1k(we2f[mt], uf, acc2, 0, 0, 0);
        }
        // D: col=edge l, row=outcol q*4+r -> one coalesced float4 per lane
        *(float4*)&outp[(size_t)(e0 + l) * DIM_A + q * 4] =
            make_float4(acc2[0] + be2v.x, acc2[1] + be2v.y,
                        acc2[2] + be2v.z, acc2[3] + be2v.w);
    }
}
#else
// Fallback (x32 MFMA + per-wave LDS round-trip), operand-swapped MFMA-2 + float4 store.
#define UPAD 268   // row stride 134 dwords (≡6 mod 32) — breaks the q-stride/l-stride alignment
__global__ __launch_bounds__(256) void k_edge(const u16* __restrict__ PQ,
                                              const float* __restrict__ attr,
                                              const int* __restrict__ rowi,
                                              const int* __restrict__ coli,
                                              const u16* __restrict__ Wct,
                                              const u16* __restrict__ We2t,
                                              const float* __restrict__ be2,
                                              float* __restrict__ outp) {
    __shared__ __align__(16) u16 ub[4][16][UPAD];
    const int tid = threadIdx.x, wid = tid >> 6, lane = tid & 63;
    const int q = lane >> 4, l = lane & 15;
    const float4 be2v = *(const float4*)&be2[q * 4];
    u16(*u)[UPAD] = ub[wid];

    s8 wcf[16];
#pragma unroll
    for (int mt = 0; mt < 16; mt++) {
        wcf[mt] = zero_s8();
        if (q < 2) wcf[mt] = *(const s8*)&Wct[(mt * 16 + l) * 16 + q * 8];
    }

    for (int tile = blockIdx.x * 4 + wid; tile < N_EDGES / 16; tile += gridDim.x * 4) {
        const int e0 = tile * 16;
        const int re = rowi[e0 + l], ce = coli[e0 + l];
        const u16* prow = PQ + (size_t)re * 512 + q * 4;
        const u16* qrow = PQ + (size_t)ce * 512 + 256 + q * 4;

        s8 af = zero_s8();
        if (q < 2) {
            const float* ap = &attr[(size_t)(e0 + l) * DIM_A + q * 8];
            float4 a0 = *(const float4*)ap;
            float4 a1 = *(const float4*)(ap + 4);
            af[0] = (short)f2bf(a0.x); af[1] = (short)f2bf(a0.y);
            af[2] = (short)f2bf(a0.z); af[3] = (short)f2bf(a0.w);
            af[4] = (short)f2bf(a1.x); af[5] = (short)f2bf(a1.y);
            af[6] = (short)f2bf(a1.z); af[7] = (short)f2bf(a1.w);
        }

#pragma unroll
        for (int mt = 0; mt < 16; mt++) {
            f4 cz = {0.f, 0.f, 0.f, 0.f};
            f4 acc = __builtin_amdgcn_mfma_f32_16x16x32_bf16(wcf[mt], af, cz, 0, 0, 0);
            ushort4 pu = *(const ushort4*)(prow + mt * 16);
            ushort4 qu = *(const ushort4*)(qrow + mt * 16);
            float t0 = bf2f(pu.x) + bf2f(qu.x) + acc[0];
            float t1 = bf2f(pu.y) + bf2f(qu.y) + acc[1];
            float t2 = bf2f(pu.z) + bf2f(qu.z) + acc[2];
            float t3 = bf2f(pu.w) + bf2f(qu.w) + acc[3];
            ushort4 o;
            o.x = f2bf(fmaxf(t0, 0.f)); o.y = f2bf(fmaxf(t1, 0.f));
            o.z = f2bf(fmaxf(t2, 0.f)); o.w = f2bf(fmaxf(t3, 0.f));
            *(ushort4*)&u[l][mt * 16 + q * 4] = o;
        }

        f4 acc2 = {0.f, 0.f, 0.f, 0.f};
#pragma unroll
        for (int ks = 0; ks < 8; ks++) {
            s8 uf = *(const s8*)&u[l][ks * 32 + q * 8];
            s8 wf = *(const s8*)&We2t[(size_t)l * DIM_H + ks * 32 + q * 8];
            acc2 = __builtin_amdgcn_mfma_f32_16x16x32_bf16(wf, uf, acc2, 0, 0, 0);
        }
        *(float4*)&outp[(size_t)(e0 + l) * DIM_A + q * 4] =
            make_float4(acc2[0] + be2v.x, acc2[1] + be2v.y,
                        acc2[2] + be2v.z, acc2[3] + be2v.w);
    }
}
#endif

extern "C" void kernel_launch(void* const* d_in, const int* in_sizes, int n_in,
                              void* d_out, int out_size, void* d_ws, size_t ws_size,
                              hipStream_t stream) {
    (void)in_sizes; (void)n_in; (void)out_size; (void)ws_size;
    const float* x    = (const float*)d_in[0];
    const int*   ei   = (const int*)d_in[1];
    const float* attr = (const float*)d_in[2];
    const float* W1   = (const float*)d_in[3];
    const float* b1   = (const float*)d_in[4];
    const float* W2   = (const float*)d_in[5];
    const float* b2   = (const float*)d_in[6];
    const float* Wo1  = (const float*)d_in[7];
    const float* bo1  = (const float*)d_in[8];
    const float* Wo2  = (const float*)d_in[9];
    const float* bo2  = (const float*)d_in[10];
    const float* We1  = (const float*)d_in[11];
    const float* be1  = (const float*)d_in[12];
    const float* We2  = (const float*)d_in[13];
    const float* be2  = (const float*)d_in[14];
    const int* rowi = ei;
    const int* coli = ei + N_EDGES;

    float* hout = (float*)d_out;                       // [N][128]
    float* eout = hout + (size_t)N_NODES * DIM_D;      // [E][16]

    char* ws = (char*)d_ws;
    size_t off = 0;
    auto nxt = [&](size_t b) -> void* {
        void* p = ws + off; off = (off + b + 255) & ~(size_t)255; return p;
    };
    float* dinv = (float*)nxt((size_t)N_NODES * 4);
    int* cnt    = (int*)nxt((size_t)N_NODES * 4);
    int* startp = (int*)nxt((size_t)(N_NODES + 1) * 4);
    int* cursor = (int*)nxt((size_t)N_NODES * 4);
    int2* pack  = (int2*)nxt((size_t)N_EDGES * 8);
    u16* W1t   = (u16*)nxt(128 * 256 * 2);
    u16* W2t   = (u16*)nxt(128 * 256 * 2);
    u16* Wo1t  = (u16*)nxt(128 * 256 * 2);
    u16* Wo2t  = (u16*)nxt(128 * 256 * 2);
    u16* Wabt  = (u16*)nxt(512 * 128 * 2);   // [512][128]: Wa^T | Wb^T
    u16* Wct   = (u16*)nxt(256 * 16 * 2);
    u16* We2t  = (u16*)nxt(16 * 256 * 2);
    float* bpq = (float*)nxt(512 * 4);
    u16* xb    = (u16*)nxt((size_t)N_NODES * DIM_D * 2);     // x cast to bf16
    float* z   = (float*)nxt((size_t)N_NODES * DIM_D * 4);   // Âx / Ây accumulator (fp32)
    u16* h1    = (u16*)nxt((size_t)N_NODES * DIM_H * 2);     // intermediate [N][256]
    u16* yb    = (u16*)nxt((size_t)N_NODES * DIM_D * 2);
    // PQ [N][512] bf16 (51.2 MB) overlays z+h1 (both dead once hout is computed)
    u16* PQb = (u16*)z;

    const int gN = (N_NODES + 255) / 256;
    const int gE = (N_EDGES + 255) / 256;

    // weight transposes (bf16)
    k_twt<<<(128 * 256 + 255) / 256, 256, 0, stream>>>(W1, W1t, 128, 256);
    k_twt<<<(128 * 256 + 255) / 256, 256, 0, stream>>>(W2, W2t, 256, 128);
    k_twt<<<(128 * 256 + 255) / 256, 256, 0, stream>>>(Wo1, Wo1t, 128, 256);
    k_twt<<<(128 * 256 + 255) / 256, 256, 0, stream>>>(Wo2, Wo2t, 256, 128);
    k_twt<<<(128 * 256 + 255) / 256, 256, 0, stream>>>(We1, Wabt, 128, 256);
    k_twt<<<(128 * 256 + 255) / 256, 256, 0, stream>>>(We1 + 128 * 256, Wabt + 256 * 128, 128, 256);
    k_twt<<<(16 * 256 + 255) / 256, 256, 0, stream>>>(We1 + 256 * 256, Wct, 16, 256);
    k_twt<<<(16 * 256 + 255) / 256, 256, 0, stream>>>(We2, We2t, 256, 16);
    k_bpq<<<2, 256, 0, stream>>>(be1, bpq);

    // ---- CSR build (once; reused by both gather layers) ----
    k_zero<<<gN, 256, 0, stream>>>(cnt);
    k_count<<<gE, 256, 0, stream>>>(coli, cnt);
    k_dinv<<<gN, 256, 0, stream>>>(cnt, dinv);
    k_scan<<<1, 1024, 0, stream>>>(cnt, startp);
    k_copy<<<gN, 256, 0, stream>>>(startp, cursor);
    k_fill<<<gE, 256, 0, stream>>>(rowi, coli, dinv, cursor, pack);

    // cast x -> bf16 (halves layer-1 gather traffic)
    k_cast<<<(N_NODES * DIM_D / 4 + 255) / 256, 256, 0, stream>>>(x, xb, N_NODES * DIM_D / 4);

    dim3 g4(391, 4), g2(391, 2), g8(391, 8);
    const int gG = (N_NODES + 3) / 4;   // 4 nodes (waves) per block
    // layer 1: z = Âx ; h1 = relu(z@W1 + b1)
    k_gather<<<gG, 256, 0, stream>>>(xb, pack, startp, dinv, z);
    k_gemm<false, false, true, true><<<g4, 256, 0, stream>>>(z, W1t, nullptr, b1, h1, N_NODES, 128, 256);
    // layer 2: y = h1@W2 ; z = Ây ; h2 = relu(z + b2) fused into next GEMM's A-stage
    k_gemm<true, false, false, true><<<g2, 256, 0, stream>>>(h1, W2t, nullptr, nullptr, yb, N_NODES, 256, 128);
    k_gather<<<gG, 256, 0, stream>>>(yb, pack, startp, dinv, z);
    // output MLP: h3 = relu(relu(z+b2)@Wo1 + bo1) ; h = h3@Wo2 + bo2 -> d_out (fp32)
    k_gemm<false, true, true, true><<<g4, 256, 0, stream>>>(z, Wo1t, b2, bo1, h1, N_NODES, 128, 256);
    k_gemm<true, false, false, false><<<g2, 256, 0, stream>>>(h1, Wo2t, nullptr, bo2, hout, N_NODES, 256, 128);
    // edge predictor precompute (single fused GEMM): PQ = [h@Wa + be1 | h@Wb]  (bf16, [N][512])
    k_gemm<false, false, false, true><<<g8, 256, 0, stream>>>(hout, Wabt, nullptr, bpq, PQb, N_NODES, 128, 512);
    // per-edge: out = relu(P[r]+Q[c]+attr@Wc)@We2 + be2
    k_edge<<<2048, 256, 0, stream>>>(PQb, attr, rowi, coli, Wct, We2t, be2, eout);
}